// Round 3
// baseline (576.623 us; speedup 1.0000x reference)
//
#include <hip/hip_runtime.h>

// Retrace loss: per-(b,k) serial backward recursion over T-1 steps, fused
// with Huber-loss mean. Memory-bound (~688 MB read, 1 float written).
// 1 thread per (b,k) chain, 256 blocks x 64 threads = 16384 threads
// (1 wave/CU). Latency hidden via explicit double-buffered register
// prefetch of C=16 time steps x 6 input streams.

namespace {
constexpr int B  = 2048;
constexpr int T  = 2049;
constexpr int K  = 8;
constexpr int TS = T - 1;        // 2048 retrace time steps
constexpr int C  = 16;           // prefetch chunk length (time steps)
constexpr int NC = TS / C;       // 128 chunks
constexpr float GAMMA_C = 0.99f;
constexpr float INV_N = 1.0f / 33554432.0f;  // 1 / (B*(T-1)*K) = 2^-25, exact

struct Chunk {
  float r[C], v[C], qt[C], lp[C], qs[C], olp[C];
};

struct Ptrs {
  const float *r, *v, *qt, *lp, *qs, *olp;
};
}  // namespace

// Load C steps (descending j) at small negative immediate offsets, then
// advance the running pointers one chunk backward.
__device__ __forceinline__ void load_chunk(Chunk& ch, Ptrs& p) {
#pragma unroll
  for (int u = 0; u < C; ++u) {
    ch.r[u]   = p.r[-(u * K)];
    ch.v[u]   = p.v[-(u * K)];
    ch.qt[u]  = p.qt[-(u * K)];
    ch.lp[u]  = p.lp[-(u * K)];
    ch.qs[u]  = p.qs[-(u * K)];
    ch.olp[u] = p.olp[-u];
  }
  p.r  -= C * K;
  p.v  -= C * K;
  p.qt -= C * K;
  p.lp -= C * K;
  p.qs -= C * K;
  p.olp -= C;
}

template <bool FIRST>
__device__ __forceinline__ void compute_chunk(const Chunk& ch, float& ret,
                                              float& acc) {
#pragma unroll
  for (int u = 0; u < C; ++u) {
    // c_j = exp(min(target_logp - orig_logp, 0)) at t = j+1 (pointers
    // pre-offset by +1 step).
    float c = __expf(fminf(ch.lp[u] - ch.olp[u], 0.0f));
    // init step (j = T-2): ret = r + g*(V + c*Qt)
    // others:              ret = r + g*(V + c*(ret - Qt))
    float inner = (FIRST && u == 0) ? ch.qt[u] : (ret - ch.qt[u]);
    ret = fmaf(GAMMA_C, fmaf(c, inner, ch.v[u]), ch.r[u]);
    // Huber(q - retrace), beta = 1
    float d  = ch.qs[u] - ret;
    float ad = fabsf(d);
    acc += (ad < 1.0f) ? (0.5f * d * d) : (ad - 0.5f);
  }
}

__global__ __launch_bounds__(64, 1) void retrace_loss_kernel(
    const float* __restrict__ q_state,  // state_trajectory_action_values
    const float* __restrict__ tq,       // target_state_trajectory_action_values
    const float* __restrict__ tv,       // target_expected_state_values
    const float* __restrict__ rew,      // rewards
    const float* __restrict__ olp,      // original_log_trajectory_action_probs (B,T)
    const float* __restrict__ tlp,      // target_log_trajectory_task_action_probs
    float* __restrict__ out) {
  const int g = blockIdx.x * 64 + threadIdx.x;
  const int b = g >> 3;
  const int k = g & 7;
  const size_t base = ((size_t)b * T) * K + k;
  const int jhi = TS - 1;  // 2047

  Ptrs p;
  // r, qs indexed at t=j; v, qt, lp, olp indexed at t=j+1.
  p.r   = rew     + base + (size_t)jhi * K;
  p.qs  = q_state + base + (size_t)jhi * K;
  p.v   = tv      + base + K + (size_t)jhi * K;
  p.qt  = tq      + base + K + (size_t)jhi * K;
  p.lp  = tlp     + base + K + (size_t)jhi * K;
  p.olp = olp     + (size_t)b * T + 1 + jhi;

  Chunk buf0, buf1;
  float ret = 0.0f, acc = 0.0f;

  load_chunk(buf0, p);           // chunk 0
  load_chunk(buf1, p);           // chunk 1 (prefetch)
  compute_chunk<true>(buf0, ret, acc);

#pragma unroll 1
  for (int ci = 1; ci < NC; ci += 2) {
    if (ci + 1 < NC) load_chunk(buf0, p);        // prefetch chunk ci+1
    compute_chunk<false>(buf1, ret, acc);        // compute chunk ci
    if (ci + 2 < NC) load_chunk(buf1, p);        // prefetch chunk ci+2
    if (ci + 1 < NC) compute_chunk<false>(buf0, ret, acc);  // compute ci+1
  }

  // Per-thread partial, exactly scaled (2^-25), wave-reduce, one atomic/block.
  acc *= INV_N;
#pragma unroll
  for (int off = 32; off > 0; off >>= 1) acc += __shfl_down(acc, off, 64);
  if (threadIdx.x == 0) atomicAdd(out, acc);
}

extern "C" void kernel_launch(void* const* d_in, const int* in_sizes, int n_in,
                              void* d_out, int out_size, void* d_ws,
                              size_t ws_size, hipStream_t stream) {
  (void)in_sizes; (void)n_in; (void)ws_size; (void)d_ws; (void)out_size;
  const float* q_state = (const float*)d_in[0];
  const float* tq      = (const float*)d_in[1];
  const float* tv      = (const float*)d_in[2];
  const float* rew     = (const float*)d_in[3];
  const float* olp     = (const float*)d_in[4];
  const float* tlp     = (const float*)d_in[5];
  float* out = (float*)d_out;

  hipMemsetAsync(out, 0, sizeof(float), stream);  // harness poisons d_out
  dim3 grid(B * K / 64);  // 256 blocks x 1 wave
  retrace_loss_kernel<<<grid, 64, 0, stream>>>(q_state, tq, tv, rew, olp, tlp,
                                               out);
}